// Round 5
// baseline (247.787 us; speedup 1.0000x reference)
//
#include <hip/hip_runtime.h>
#include <math.h>

// (B, N, D) = (16, 2048, 128)
constexpr int Bc = 16;
constexpr int Nc = 2048;
constexpr int Dc = 128;
constexpr int NCHUNK = Nc / 64;          // 32 key-chunks of 64
constexpr float SCALE_F = 0.08838834764831845f;  // 1/sqrt(128)

typedef __bf16 bf16x8 __attribute__((ext_vector_type(8)));
typedef __bf16 bf16x4 __attribute__((ext_vector_type(4)));
typedef float  f32x4  __attribute__((ext_vector_type(4)));

// ws layout: Kpack 8MB | Vpack 8MB | bias_packed 8.65MB | partials 38.3MB
constexpr size_t KPACK_BYTES = (size_t)Bc * NCHUNK * 16 * 64 * 16;
constexpr size_t VPACK_BYTES = KPACK_BYTES;
constexpr int NUNITS = 1056;             // sum_t C(t), C(t)=t/2+1, t in [0,64)
constexpr size_t BIASP_BYTES = (size_t)NUNITS * 2048 * 4;
constexpr int CHUNK_ELEMS = 16 * 64 * 8; // 8192 bf16 = 16KB per chunk
// split-C partials: 72 sliced units per b (tiles t=8..31), each 64x128 O + m[64] + l[64]
constexpr int PART_FLOATS = 64 * 128 + 64 + 64;   // 8320
constexpr size_t PART_BYTES = (size_t)Bc * 72 * PART_FLOATS * 4;

// prefix of causal chunk counts over 32-row tiles: ftri(t)=sum_{t'<t}(t'/2+1)
__device__ __forceinline__ int ftri(int t) {
    const int m = t >> 1;
    return (t & 1) ? (m + 1) * (m + 1) : m * (m + 1);
}

__device__ __forceinline__ void gload_lds16(const __bf16* gsrc, __bf16* ldst) {
    // 16B per lane; LDS dest = wave-uniform base + lane*16 (HW rule).
    __builtin_amdgcn_global_load_lds(
        (const __attribute__((address_space(1))) unsigned int*)gsrc,
        (__attribute__((address_space(3))) unsigned int*)ldst, 16, 0, 0);
}

// ---- DPP 16-lane row reductions (VALU pipe, no LDS/lgkm) ----
template<int CTRL>
__device__ __forceinline__ float dpp_mv(float v) {
    return __builtin_bit_cast(float,
        __builtin_amdgcn_update_dpp(0, __builtin_bit_cast(int, v),
                                    CTRL, 0xF, 0xF, true));
}
__device__ __forceinline__ float rmax16(float v) {
    v = fmaxf(v, dpp_mv<0xB1>(v));
    v = fmaxf(v, dpp_mv<0x4E>(v));
    v = fmaxf(v, dpp_mv<0x141>(v));
    v = fmaxf(v, dpp_mv<0x140>(v));
    return v;
}
__device__ __forceinline__ float rsum16(float v) {
    v += dpp_mv<0xB1>(v);
    v += dpp_mv<0x4E>(v);
    v += dpp_mv<0x141>(v);
    v += dpp_mv<0x140>(v);
    return v;
}

// ---- fused prep (verbatim from R3/R4 — correctness-proven) ----
__global__ __launch_bounds__(256) void prep_fused(
    const float* __restrict__ K, const float* __restrict__ V,
    const int* __restrict__ imask,
    const float* __restrict__ b0, const float* __restrict__ b1,
    const float* __restrict__ b2, const float* __restrict__ b3,
    __bf16* __restrict__ Kp, __bf16* __restrict__ Vp, float* __restrict__ bsp)
{
    __shared__ __align__(16) __bf16 Ks[64][136];
    __shared__ __align__(16) __bf16 Vs[64][136];
    __shared__ __align__(16) float  Ts[32][68];
    const int bid = blockIdx.x;
    const int tid = threadIdx.x;

    if (bid >= 512) {
        const int u = bid - 512;               // unit in [0,1056)
        int t = 0;
        while (ftri(t + 1) <= u) ++t;          // <=64 scalar iters, once per block
        const int c = u - ftri(t);

        #pragma unroll
        for (int i = 0; i < 2; ++i) {
            const int v = tid + 256 * i;
            const int row = v >> 4, c4 = v & 15;
            const size_t g = (size_t)(t * 32 + row) * Nc + c * 64 + c4 * 4;
            const float4 a = *(const float4*)(b0 + g);
            const float4 d = *(const float4*)(b1 + g);
            const float4 e = *(const float4*)(b2 + g);
            const float4 f = *(const float4*)(b3 + g);
            float4 s;
            s.x = a.x + d.x + e.x + f.x;
            s.y = a.y + d.y + e.y + f.y;
            s.z = a.z + d.z + e.z + f.z;
            s.w = a.w + d.w + e.w + f.w;
            *(float4*)&Ts[row][c4 * 4] = s;
        }
        __syncthreads();

        const int lane = tid >> 2;
        const int quad = lane >> 4, l15 = lane & 15;
        const int k0 = (tid & 3) * 8;
        float* outp = bsp + (size_t)u * 2048;
        #pragma unroll
        for (int g2 = 0; g2 < 2; ++g2) {
            const int k = k0 + g2 * 4;
            const int h = (k >> 4) & 1, jt = (k >> 2) & 3;
            float4 o;
            o.x = Ts[h * 16 + quad * 4 + 0][jt * 16 + l15];
            o.y = Ts[h * 16 + quad * 4 + 1][jt * 16 + l15];
            o.z = Ts[h * 16 + quad * 4 + 2][jt * 16 + l15];
            o.w = Ts[h * 16 + quad * 4 + 3][jt * 16 + l15];
            ((float4*)outp)[tid * 2 + g2] = o;
        }
        return;
    }

    const int c = bid & 31;
    const int b = bid >> 5;
    const int m0 = c * 64;
    const float* Kb = K + (size_t)b * Nc * Dc;
    const float* Vb = V + (size_t)b * Nc * Dc;
    const int* imb = imask + b * Nc;

    #pragma unroll
    for (int it = 0; it < 8; ++it) {
        const int idx = it * 256 + tid;
        const int row = idx >> 5;
        const int c4  = idx & 31;
        const int gm  = m0 + row;
        const float msk = imb[gm] ? 1.0f : 0.0f;
        const float4 kf = ((const float4*)(Kb + (size_t)gm * Dc))[c4];
        const float4 vf = ((const float4*)(Vb + (size_t)gm * Dc))[c4];
        bf16x4 kb, vb;
        kb[0] = (__bf16)(kf.x * msk); kb[1] = (__bf16)(kf.y * msk);
        kb[2] = (__bf16)(kf.z * msk); kb[3] = (__bf16)(kf.w * msk);
        vb[0] = (__bf16)(vf.x * msk); vb[1] = (__bf16)(vf.y * msk);
        vb[2] = (__bf16)(vf.z * msk); vb[3] = (__bf16)(vf.w * msk);
        *(bf16x4*)&Ks[row][c4 * 4] = kb;
        *(bf16x4*)&Vs[row][c4 * 4] = vb;
    }
    __syncthreads();

    const size_t chunk_base = (size_t)(b * NCHUNK + c) * CHUNK_ELEMS;
    #pragma unroll
    for (int i = 0; i < 4; ++i) {
        const int s = i * 256 + tid;
        const int f = s >> 6;
        const int l = s & 63;
        const int quad = (l >> 4) & 3;
        const int l15  = l & 15;
        {   // K frag f=jt*4+kd
            const int jt = f >> 2, kd = f & 3;
            const bf16x8 kv = *(const bf16x8*)&Ks[jt * 16 + l15][kd * 32 + quad * 8];
            *(bf16x8*)&Kp[chunk_base + (size_t)f * 512 + l * 8] = kv;
        }
        {   // V frag f=kj*8+dt
            const int kj = f >> 3, dt = f & 7;
            bf16x8 vv;
            #pragma unroll
            for (int j = 0; j < 8; ++j)
                vv[j] = Vs[kj * 32 + quad * 8 + j][dt * 16 + l15];
            *(bf16x8*)&Vp[chunk_base + (size_t)f * 512 + l * 8] = vv;
        }
    }
}

// ---- main: split-C pipelined flash attention, K staged / V direct ----
// vs R4 (68us): Vl staging dropped -> LDS 73->41KB -> 3 blocks/CU (12 waves).
// V fragments read direct from the L2-resident pack, no barrier needed:
//   kj=0 loads issued at iteration top (hidden under mask+softmax+P-store),
//   kj=1 loads issued after the P-store (hidden under lgkm wait + PV kj0).
// Rescale-skip (__any guard, proven R1/R3) removes the 32-mul oacc rescale
// on chunks where no row max grows. No launch-bounds min-wave hint (R3 spill
// lesson); predicted peak live regs ~150 < 168 (3 waves/SIMD cap).
template<bool SPLIT>
__global__ __launch_bounds__(256) void attn_pipe3(
    const float* __restrict__ Q,
    const __bf16* __restrict__ Kp, const __bf16* __restrict__ Vp,
    const float* __restrict__ biasp, const int* __restrict__ emask,
    float* __restrict__ out, float* __restrict__ part)
{
    __shared__ __align__(16) __bf16 Kl[2][16 * 512];   // 2 x 16KB
    __shared__ __align__(16) __bf16 Pl[4][16][72];

    const int tid  = threadIdx.x;
    const int w    = tid >> 6;
    const int lane = tid & 63;
    const int quad = lane >> 4;
    const int l15  = lane & 15;
    const int b = blockIdx.x;

    int t, c0, cend, pidx;
    bool direct;
    if (SPLIT) {
        const int u = 79 - blockIdx.y;     // heavy-first dispatch
        int s;
        if (u < 8)       { t = u;                 s = 0; }
        else if (u < 24) { t = 8  + ((u - 8) >> 1);  s = (u - 8) & 1; }
        else if (u < 48) { t = 16 + (u - 24) / 3;    s = (u - 24) % 3; }
        else             { t = 24 + ((u - 48) >> 2); s = (u - 48) & 3; }
        c0 = s * 8;
        cend = min(t + 1, c0 + 8);
        direct = (u < 8);
        pidx = u - 8;
    } else {
        const int y = blockIdx.y;
        t = (y < 16) ? y : (47 - y);       // pair sums = 33 chunks
        c0 = 0; cend = t + 1; direct = true; pidx = 0;
    }

    const int q0w = t * 64 + w * 16;
    const int t32 = t * 2 + (w >> 1);      // 32-row bias-tile index
    const int hh  = w & 1;                 // half within the bias tile
    const int fb32 = ftri(t32);

    const float*  Qb  = Q + (size_t)b * Nc * Dc;
    const __bf16* Kpb = Kp + (size_t)b * NCHUNK * CHUNK_ELEMS;
    const __bf16* Vpb = Vp + (size_t)b * NCHUNK * CHUNK_ELEMS;
    // packed bias fragments for this 16-row group, chunk c:
    //   f32x4 index (fb32+c)*512 + lane*8 + hh*4 + jt
    const f32x4* bfrag = (const f32x4*)biasp + (size_t)lane * 8 + hh * 4;

    // ---- Q fragments (emask + SCALE folded) ----
    bf16x8 qfrag[4];
    {
        const int row = q0w + l15;
        const float qs = emask[b * Nc + row] ? SCALE_F : 0.0f;
        const float4* qr = (const float4*)(Qb + (size_t)row * Dc);
        #pragma unroll
        for (int kd = 0; kd < 4; ++kd) {
            const float4 xx = qr[kd * 8 + quad * 2];
            const float4 yy = qr[kd * 8 + quad * 2 + 1];
            qfrag[kd][0] = (__bf16)(xx.x * qs); qfrag[kd][1] = (__bf16)(xx.y * qs);
            qfrag[kd][2] = (__bf16)(xx.z * qs); qfrag[kd][3] = (__bf16)(xx.w * qs);
            qfrag[kd][4] = (__bf16)(yy.x * qs); qfrag[kd][5] = (__bf16)(yy.y * qs);
            qfrag[kd][6] = (__bf16)(yy.z * qs); qfrag[kd][7] = (__bf16)(yy.w * qs);
        }
    }

    f32x4 oacc[8];
    #pragma unroll
    for (int dt = 0; dt < 8; ++dt) { oacc[dt][0]=0.f; oacc[dt][1]=0.f; oacc[dt][2]=0.f; oacc[dt][3]=0.f; }
    float mrun[4] = {-INFINITY, -INFINITY, -INFINITY, -INFINITY};
    float lrun[4] = {0.f, 0.f, 0.f, 0.f};

    const int nch = cend - c0;

    // ---- prologue: DMA K(c0) -> buf0; bias(c0) ----
    #pragma unroll
    for (int i = 0; i < 4; ++i) {
        const int seg = w * 4 + i;
        gload_lds16(Kpb + (size_t)c0 * CHUNK_ELEMS + seg * 512 + lane * 8, &Kl[0][seg * 512]);
    }
    f32x4 binit[4];
    #pragma unroll
    for (int jt = 0; jt < 4; ++jt)
        binit[jt] = bfrag[(size_t)(fb32 + c0) * 512 + jt];
    __syncthreads();   // drain: chunk-c0 K DMA landed

    // ---- QK(c0) with bias as C-init ----
    f32x4 sc[4];
    #pragma unroll
    for (int jt = 0; jt < 4; ++jt) sc[jt] = binit[jt];
    #pragma unroll
    for (int jt = 0; jt < 4; ++jt)
        #pragma unroll
        for (int kd = 0; kd < 4; ++kd) {
            const bf16x8 bfr = *(const bf16x8*)&Kl[0][(jt * 4 + kd) * 512 + lane * 8];
            sc[jt] = __builtin_amdgcn_mfma_f32_16x16x32_bf16(qfrag[kd], bfr, sc[jt], 0, 0, 0);
        }
    if (nch > 1) {
        #pragma unroll
        for (int i = 0; i < 4; ++i) {
            const int seg = w * 4 + i;
            gload_lds16(Kpb + (size_t)(c0 + 1) * CHUNK_ELEMS + seg * 512 + lane * 8, &Kl[1][seg * 512]);
        }
        #pragma unroll
        for (int jt = 0; jt < 4; ++jt)
            binit[jt] = bfrag[(size_t)(fb32 + c0 + 1) * 512 + jt];
    }

    for (int c = c0; c < cend; ++c) {
        const int cb = (c - c0) & 1;
        const __bf16* vc = Vpb + (size_t)c * CHUNK_ELEMS;

        // ---- V kj=0 prefetch (direct from L2 pack; no barrier needed) ----
        bf16x8 va[8];
        #pragma unroll
        for (int dt = 0; dt < 8; ++dt)
            va[dt] = *(const bf16x8*)&vc[(size_t)dt * 512 + lane * 8];

        // ---- causal mask on the diagonal chunk (bias already in sc) ----
        if (c == t) {
            const int m0 = c * 64;
            #pragma unroll
            for (int jt = 0; jt < 4; ++jt)
                #pragma unroll
                for (int reg = 0; reg < 4; ++reg) {
                    const int gr = q0w + quad * 4 + reg;
                    const int gc = m0 + jt * 16 + l15;
                    if (gc > gr) sc[jt][reg] = -INFINITY;
                }
        }

        // ---- online softmax; exact rescale-skip when no row max grows ----
        float mx[4];
        int grow = 0;
        #pragma unroll
        for (int reg = 0; reg < 4; ++reg) {
            float m = fmaxf(fmaxf(sc[0][reg], sc[1][reg]), fmaxf(sc[2][reg], sc[3][reg]));
            m = rmax16(m);
            mx[reg] = m;
            grow |= (m > mrun[reg]);
        }
        if (__any(grow)) {   // wave-uniform; skip path is numerically exact
            #pragma unroll
            for (int reg = 0; reg < 4; ++reg) {
                const float mn = fmaxf(mrun[reg], mx[reg]);
                const float alpha = __expf(mrun[reg] - mn);  // first chunk: exp(-inf)=0
                mrun[reg] = mn;
                lrun[reg] *= alpha;
                #pragma unroll
                for (int dt = 0; dt < 8; ++dt) oacc[dt][reg] *= alpha;
            }
        }
        #pragma unroll
        for (int reg = 0; reg < 4; ++reg) {
            float ls = 0.f;
            #pragma unroll
            for (int jt = 0; jt < 4; ++jt) {
                const float pv = __expf(sc[jt][reg] - mrun[reg]);  // masked: exp(-inf)=0
                sc[jt][reg] = pv;
                ls += pv;
            }
            lrun[reg] += rsum16(ls);
        }

        // ---- P: C-layout -> LDS -> A-layout ----
        #pragma unroll
        for (int jt = 0; jt < 4; ++jt)
            #pragma unroll
            for (int reg = 0; reg < 4; ++reg)
                Pl[w][quad * 4 + reg][jt * 16 + l15] = (__bf16)sc[jt][reg];
        // same-wave write->read; compiler inserts lgkmcnt wait

        // ---- V kj=1 prefetch (hidden under lgkm wait + PV kj0) ----
        bf16x8 vb8[8];
        #pragma unroll
        for (int dt = 0; dt < 8; ++dt)
            vb8[dt] = *(const bf16x8*)&vc[(size_t)(8 + dt) * 512 + lane * 8];

        // ---- O += P V ----
        {
            const bf16x8 pa0 = *(const bf16x8*)&Pl[w][l15][quad * 8];
            #pragma unroll
            for (int dt = 0; dt < 8; ++dt)
                oacc[dt] = __builtin_amdgcn_mfma_f32_16x16x32_bf16(pa0, va[dt], oacc[dt], 0, 0, 0);
            const bf16x8 pa1 = *(const bf16x8*)&Pl[w][l15][32 + quad * 8];
            #pragma unroll
            for (int dt = 0; dt < 8; ++dt)
                oacc[dt] = __builtin_amdgcn_mfma_f32_16x16x32_bf16(pa1, vb8[dt], oacc[dt], 0, 0, 0);
        }

        // single barrier: all waves done reading Kl[cb]; vmcnt drain covers
        // K DMA(c+1) (issued a full iteration ago -> near-free).
        __syncthreads();

        const bool n1 = (c + 1) < cend;
        const bool n2 = (c + 2) < cend;

        // ---- DMA K chunk c+2 into buf[cb] (K(c) retired) ----
        if (n2) {
            const size_t off = (size_t)(c + 2) * CHUNK_ELEMS;
            #pragma unroll
            for (int i = 0; i < 4; ++i) {
                const int seg = w * 4 + i;
                gload_lds16(Kpb + off + seg * 512 + lane * 8, &Kl[cb][seg * 512]);
            }
        }

        // ---- QK(c+1) from Kl[cb^1]; bias (prefetched last iter) as C-init ----
        if (n1) {
            #pragma unroll
            for (int jt = 0; jt < 4; ++jt) sc[jt] = binit[jt];
            #pragma unroll
            for (int jt = 0; jt < 4; ++jt)
                #pragma unroll
                for (int kd = 0; kd < 4; ++kd) {
                    const bf16x8 bfr = *(const bf16x8*)&Kl[cb ^ 1][(jt * 4 + kd) * 512 + lane * 8];
                    sc[jt] = __builtin_amdgcn_mfma_f32_16x16x32_bf16(qfrag[kd], bfr, sc[jt], 0, 0, 0);
                }
        }
        if (n2) {
            #pragma unroll
            for (int jt = 0; jt < 4; ++jt)
                binit[jt] = bfrag[(size_t)(fb32 + c + 2) * 512 + jt];
        }
    }

    // ---- epilogue ----
    if (direct) {
        #pragma unroll
        for (int reg = 0; reg < 4; ++reg) {
            const float inv = 1.0f / lrun[reg];
            const int gr = q0w + quad * 4 + reg;
            float* orow = out + ((size_t)b * Nc + gr) * Dc;
            #pragma unroll
            for (int dt = 0; dt < 8; ++dt)
                orow[dt * 16 + l15] = oacc[dt][reg] * inv;
        }
    } else {
        float* pb = part + (size_t)(b * 72 + pidx) * PART_FLOATS;
        #pragma unroll
        for (int reg = 0; reg < 4; ++reg) {
            const int lr = w * 16 + quad * 4 + reg;
            #pragma unroll
            for (int dt = 0; dt < 8; ++dt)
                pb[lr * 128 + dt * 16 + l15] = oacc[dt][reg];
            if (l15 == 0) {
                pb[8192 + lr] = mrun[reg];
                pb[8256 + lr] = lrun[reg];
            }
        }
    }
}

// ---- merge <=4 split-C partials per (b, tile t=8..31) ----
__global__ __launch_bounds__(256) void merge_parts(
    const float* __restrict__ part, float* __restrict__ out)
{
    const int b = blockIdx.x;
    const int t = 8 + blockIdx.y;
    const int S = (t < 16) ? 2 : ((t < 24) ? 3 : 4);
    const int pbase = (t < 16) ? 2 * (t - 8)
                    : (t < 24) ? 16 + 3 * (t - 16)
                               : 40 + 4 * (t - 24);
    const int r  = threadIdx.x >> 2;       // row 0..63
    const int cq = threadIdx.x & 3;        // col quarter (32 cols)
    const float* p0 = part + (size_t)(b * 72 + pbase) * PART_FLOATS;

    float m[4], a[4];
    float mstar = -INFINITY;
    #pragma unroll
    for (int s = 0; s < 4; ++s)
        if (s < S) { m[s] = p0[(size_t)s * PART_FLOATS + 8192 + r]; mstar = fmaxf(mstar, m[s]); }
    float lsum = 0.f;
    #pragma unroll
    for (int s = 0; s < 4; ++s)
        if (s < S) {
            a[s] = __expf(m[s] - mstar);
            lsum += p0[(size_t)s * PART_FLOATS + 8256 + r] * a[s];
        }
    const float inv = 1.0f / lsum;

    float* orow = out + ((size_t)b * Nc + t * 64 + r) * Dc + cq * 32;
    #pragma unroll
    for (int i = 0; i < 8; ++i) {
        float x = 0.f, y = 0.f, z = 0.f, ww = 0.f;
        #pragma unroll
        for (int s = 0; s < 4; ++s)
            if (s < S) {
                const f32x4 v = *(const f32x4*)&p0[(size_t)s * PART_FLOATS + r * 128 + cq * 32 + i * 4];
                x += v[0] * a[s]; y += v[1] * a[s]; z += v[2] * a[s]; ww += v[3] * a[s];
            }
        f32x4 o; o[0] = x * inv; o[1] = y * inv; o[2] = z * inv; o[3] = ww * inv;
        *(f32x4*)&orow[i * 4] = o;
    }
}

// ---- legacy fallback (in-kernel staging, 4 bias reads) for tiny ws ----
__global__ __launch_bounds__(256) void attn_mfma_legacy(
    const float* __restrict__ Q, const float* __restrict__ K, const float* __restrict__ V,
    const float* __restrict__ p0, const float* __restrict__ p1,
    const float* __restrict__ p2, const float* __restrict__ p3,
    const int* __restrict__ imask, const int* __restrict__ emask,
    float* __restrict__ out)
{
    __shared__ __align__(16) __bf16 Klds[64][136];
    __shared__ __align__(16) __bf16 Vt[128][72];
    __shared__ __align__(16) __bf16 Plds[4][16][72];
    const int tid  = threadIdx.x;
    const int w    = tid >> 6;
    const int lane = tid & 63;
    const int quad = lane >> 4;
    const int l15  = lane & 15;
    const int b = blockIdx.y;
    const int x = blockIdx.x, yy = blockIdx.y;
    const int ti = (yy < 8) ? x : (31 - x);
    const int q0 = ti * 64, q0w = q0 + w * 16;
    const float* Qb = Q + (size_t)b * Nc * Dc;
    const float* Kb = K + (size_t)b * Nc * Dc;
    const float* Vb = V + (size_t)b * Nc * Dc;
    const int* imb = imask + b * Nc;

    bf16x8 qfrag[4];
    {
        const int row = q0w + l15;
        const float qs = emask[b * Nc + row] ? SCALE_F : 0.0f;
        const float4* qr = (const float4*)(Qb + (size_t)row * Dc);
        #pragma unroll
        for (int kd = 0; kd < 4; ++kd) {
            const float4 xv = qr[kd * 8 + quad * 2];
            const float4 yv = qr[kd * 8 + quad * 2 + 1];
            qfrag[kd][0]=(__bf16)(xv.x*qs); qfrag[kd][1]=(__bf16)(xv.y*qs);
            qfrag[kd][2]=(__bf16)(xv.z*qs); qfrag[kd][3]=(__bf16)(xv.w*qs);
            qfrag[kd][4]=(__bf16)(yv.x*qs); qfrag[kd][5]=(__bf16)(yv.y*qs);
            qfrag[kd][6]=(__bf16)(yv.z*qs); qfrag[kd][7]=(__bf16)(yv.w*qs);
        }
    }
    f32x4 oacc[8];
    #pragma unroll
    for (int dt = 0; dt < 8; ++dt){oacc[dt][0]=0.f;oacc[dt][1]=0.f;oacc[dt][2]=0.f;oacc[dt][3]=0.f;}
    float mrun[4]={-INFINITY,-INFINITY,-INFINITY,-INFINITY}, lrun[4]={0.f,0.f,0.f,0.f};

    for (int m0 = 0; m0 <= q0; m0 += 64) {
        __syncthreads();
        #pragma unroll
        for (int it = 0; it < 8; ++it) {
            const int idx = it * 256 + tid;
            const int row = idx >> 5, c4 = idx & 31;
            const int gm = m0 + row;
            const float msk = imb[gm] ? 1.0f : 0.0f;
            const float4 kf = ((const float4*)(Kb + (size_t)gm * Dc))[c4];
            const float4 vf = ((const float4*)(Vb + (size_t)gm * Dc))[c4];
            bf16x4 kb;
            kb[0]=(__bf16)(kf.x*msk); kb[1]=(__bf16)(kf.y*msk);
            kb[2]=(__bf16)(kf.z*msk); kb[3]=(__bf16)(kf.w*msk);
            *(bf16x4*)&Klds[row][c4*4] = kb;
            Vt[c4*4+0][row]=(__bf16)(vf.x*msk); Vt[c4*4+1][row]=(__bf16)(vf.y*msk);
            Vt[c4*4+2][row]=(__bf16)(vf.z*msk); Vt[c4*4+3][row]=(__bf16)(vf.w*msk);
        }
        __syncthreads();
        f32x4 sc[4];
        #pragma unroll
        for (int jt = 0; jt < 4; ++jt){sc[jt][0]=0.f;sc[jt][1]=0.f;sc[jt][2]=0.f;sc[jt][3]=0.f;}
        #pragma unroll
        for (int jt = 0; jt < 4; ++jt)
            #pragma unroll
            for (int kd = 0; kd < 4; ++kd) {
                const bf16x8 bfr = *(const bf16x8*)&Klds[jt*16+l15][kd*32+quad*8];
                sc[jt] = __builtin_amdgcn_mfma_f32_16x16x32_bf16(qfrag[kd], bfr, sc[jt], 0, 0, 0);
            }
        #pragma unroll
        for (int jt = 0; jt < 4; ++jt)
            #pragma unroll
            for (int reg = 0; reg < 4; ++reg) {
                const int gr = q0w + quad*4 + reg;
                const int gc = m0 + jt*16 + l15;
                const size_t boff = (size_t)gr * Nc + gc;
                const float bsx = p0[boff] + p1[boff] + p2[boff] + p3[boff];
                const float v = sc[jt][reg] + bsx;
                sc[jt][reg] = (gc > gr) ? -INFINITY : v;
            }
        #pragma unroll
        for (int reg = 0; reg < 4; ++reg) {
            float mx = fmaxf(fmaxf(sc[0][reg], sc[1][reg]), fmaxf(sc[2][reg], sc[3][reg]));
            mx = rmax16(mx);
            const float mn = fmaxf(mrun[reg], mx);
            const float alpha = __expf(mrun[reg] - mn);
            mrun[reg] = mn; lrun[reg] *= alpha;
            #pragma unroll
            for (int dt = 0; dt < 8; ++dt) oacc[dt][reg] *= alpha;
            float ls = 0.f;
            #pragma unroll
            for (int jt = 0; jt < 4; ++jt) {
                const float pv = __expf(sc[jt][reg] - mn);
                sc[jt][reg] = pv; ls += pv;
            }
            lrun[reg] += rsum16(ls);
        }
        #pragma unroll
        for (int jt = 0; jt < 4; ++jt)
            #pragma unroll
            for (int reg = 0; reg < 4; ++reg)
                Plds[w][quad*4+reg][jt*16+l15] = (__bf16)sc[jt][reg];
        #pragma unroll
        for (int kj = 0; kj < 2; ++kj) {
            const bf16x8 pa = *(const bf16x8*)&Plds[w][l15][kj*32+quad*8];
            #pragma unroll
            for (int dt = 0; dt < 8; ++dt) {
                const bf16x8 vb = *(const bf16x8*)&Vt[dt*16+l15][kj*32+quad*8];
                oacc[dt] = __builtin_amdgcn_mfma_f32_16x16x32_bf16(pa, vb, oacc[dt], 0, 0, 0);
            }
        }
    }
    #pragma unroll
    for (int reg = 0; reg < 4; ++reg) {
        const float inv = 1.0f / lrun[reg];
        const int gr = q0w + quad*4 + reg;
        float* orow = out + ((size_t)b * Nc + gr) * Dc;
        #pragma unroll
        for (int dt = 0; dt < 8; ++dt)
            orow[dt*16+l15] = oacc[dt][reg] * inv;
    }
}

extern "C" void kernel_launch(void* const* d_in, const int* in_sizes, int n_in,
                              void* d_out, int out_size, void* d_ws, size_t ws_size,
                              hipStream_t stream) {
    const float* Q  = (const float*)d_in[0];
    const float* K  = (const float*)d_in[1];
    const float* V  = (const float*)d_in[2];
    const float* b0 = (const float*)d_in[3];
    const float* b1 = (const float*)d_in[4];
    const float* b2 = (const float*)d_in[5];
    const float* b3 = (const float*)d_in[6];
    const int* im   = (const int*)d_in[7];
    const int* em   = (const int*)d_in[8];
    float* out      = (float*)d_out;

    const size_t need_full  = KPACK_BYTES + VPACK_BYTES + BIASP_BYTES;
    const size_t need_split = need_full + PART_BYTES;

    if (ws_size >= need_full) {
        __bf16* Kp  = (__bf16*)d_ws;
        __bf16* Vp  = (__bf16*)((char*)d_ws + KPACK_BYTES);
        float*  bsp = (float*)((char*)d_ws + KPACK_BYTES + VPACK_BYTES);
        float*  prt = (float*)((char*)d_ws + need_full);
        prep_fused<<<512 + NUNITS, 256, 0, stream>>>(
            K, V, im, b0, b1, b2, b3, Kp, Vp, bsp);
        if (ws_size >= need_split) {
            attn_pipe3<true><<<dim3(Bc, 80), 256, 0, stream>>>(
                Q, Kp, Vp, bsp, em, out, prt);
            merge_parts<<<dim3(Bc, 24), 256, 0, stream>>>(prt, out);
        } else {
            attn_pipe3<false><<<dim3(Bc, 32), 256, 0, stream>>>(
                Q, Kp, Vp, bsp, em, out, nullptr);
        }
    } else {
        attn_mfma_legacy<<<dim3(NCHUNK, Bc), 256, 0, stream>>>(
            Q, K, V, b0, b1, b2, b3, im, em, out);
    }
}

// Round 6
// 234.210 us; speedup vs baseline: 1.0580x; 1.0580x over previous
//
#include <hip/hip_runtime.h>
#include <math.h>

// (B, N, D) = (16, 2048, 128)
constexpr int Bc = 16;
constexpr int Nc = 2048;
constexpr int Dc = 128;
constexpr int NCHUNK = Nc / 64;          // 32 key-chunks of 64
constexpr float SCALE_F = 0.08838834764831845f;  // 1/sqrt(128)

typedef __bf16 bf16x8 __attribute__((ext_vector_type(8)));
typedef __bf16 bf16x4 __attribute__((ext_vector_type(4)));
typedef float  f32x4  __attribute__((ext_vector_type(4)));

// ws layout: Kpack 8MB | Vpack 8MB | bias_packed 8.65MB | partials 38.3MB
constexpr size_t KPACK_BYTES = (size_t)Bc * NCHUNK * 16 * 64 * 16;
constexpr size_t VPACK_BYTES = KPACK_BYTES;
constexpr int NUNITS = 1056;             // sum_t C(t), C(t)=t/2+1, t in [0,64)
constexpr size_t BIASP_BYTES = (size_t)NUNITS * 2048 * 4;
constexpr int CHUNK_ELEMS = 16 * 64 * 8; // 8192 bf16 = 16KB per chunk
// split-C partials: 72 sliced units per b (tiles t=8..31), each 64x128 O + m[64] + l[64]
constexpr int PART_FLOATS = 64 * 128 + 64 + 64;   // 8320
constexpr size_t PART_BYTES = (size_t)Bc * 72 * PART_FLOATS * 4;

// Persistent-block schedule: the 80 split units of one b packed into 32 slots
// of 16-17 chunks (LPT). Unit ids use the R4 enumeration (decoded in-kernel).
// Slots 0-15 carry 3 units (17 chunks), slots 16-31 carry 2 (16 chunks).
__device__ __constant__ int SLOT_UNITS[32][3] = {
    { 7,  6,  1}, { 8, 21, 11}, {10, 44, 29}, {12, 75, 55},
    {14,  5,  2}, {16, 19, 13}, {18, 41, 32}, {20, 71, 59},
    {22,  4,  3}, {23, 17, 15}, {24, 38, 35}, {25, 67, 63},
    {27, 28,  0}, {30, 31,  9}, {33, 34, 26}, {36, 37, 51},
    {39, 40, -1}, {42, 43, -1}, {45, 46, -1}, {47, 48, -1},
    {49, 50, -1}, {52, 53, -1}, {54, 56, -1}, {57, 58, -1},
    {60, 61, -1}, {62, 64, -1}, {65, 66, -1}, {68, 69, -1},
    {70, 72, -1}, {73, 74, -1}, {76, 77, -1}, {78, 79, -1}
};

// prefix of causal chunk counts over 32-row tiles: ftri(t)=sum_{t'<t}(t'/2+1)
__device__ __forceinline__ int ftri(int t) {
    const int m = t >> 1;
    return (t & 1) ? (m + 1) * (m + 1) : m * (m + 1);
}

__device__ __forceinline__ void gload_lds16(const __bf16* gsrc, __bf16* ldst) {
    // 16B per lane; LDS dest = wave-uniform base + lane*16 (HW rule).
    __builtin_amdgcn_global_load_lds(
        (const __attribute__((address_space(1))) unsigned int*)gsrc,
        (__attribute__((address_space(3))) unsigned int*)ldst, 16, 0, 0);
}

// ---- DPP 16-lane row reductions (VALU pipe, no LDS/lgkm) ----
template<int CTRL>
__device__ __forceinline__ float dpp_mv(float v) {
    return __builtin_bit_cast(float,
        __builtin_amdgcn_update_dpp(0, __builtin_bit_cast(int, v),
                                    CTRL, 0xF, 0xF, true));
}
__device__ __forceinline__ float rmax16(float v) {
    v = fmaxf(v, dpp_mv<0xB1>(v));
    v = fmaxf(v, dpp_mv<0x4E>(v));
    v = fmaxf(v, dpp_mv<0x141>(v));
    v = fmaxf(v, dpp_mv<0x140>(v));
    return v;
}
__device__ __forceinline__ float rsum16(float v) {
    v += dpp_mv<0xB1>(v);
    v += dpp_mv<0x4E>(v);
    v += dpp_mv<0x141>(v);
    v += dpp_mv<0x140>(v);
    return v;
}

// ---- fused prep (verbatim — correctness-proven) ----
__global__ __launch_bounds__(256) void prep_fused(
    const float* __restrict__ K, const float* __restrict__ V,
    const int* __restrict__ imask,
    const float* __restrict__ b0, const float* __restrict__ b1,
    const float* __restrict__ b2, const float* __restrict__ b3,
    __bf16* __restrict__ Kp, __bf16* __restrict__ Vp, float* __restrict__ bsp)
{
    __shared__ __align__(16) __bf16 Ks[64][136];
    __shared__ __align__(16) __bf16 Vs[64][136];
    __shared__ __align__(16) float  Ts[32][68];
    const int bid = blockIdx.x;
    const int tid = threadIdx.x;

    if (bid >= 512) {
        const int u = bid - 512;               // unit in [0,1056)
        int t = 0;
        while (ftri(t + 1) <= u) ++t;          // <=64 scalar iters, once per block
        const int c = u - ftri(t);

        #pragma unroll
        for (int i = 0; i < 2; ++i) {
            const int v = tid + 256 * i;
            const int row = v >> 4, c4 = v & 15;
            const size_t g = (size_t)(t * 32 + row) * Nc + c * 64 + c4 * 4;
            const float4 a = *(const float4*)(b0 + g);
            const float4 d = *(const float4*)(b1 + g);
            const float4 e = *(const float4*)(b2 + g);
            const float4 f = *(const float4*)(b3 + g);
            float4 s;
            s.x = a.x + d.x + e.x + f.x;
            s.y = a.y + d.y + e.y + f.y;
            s.z = a.z + d.z + e.z + f.z;
            s.w = a.w + d.w + e.w + f.w;
            *(float4*)&Ts[row][c4 * 4] = s;
        }
        __syncthreads();

        const int lane = tid >> 2;
        const int quad = lane >> 4, l15 = lane & 15;
        const int k0 = (tid & 3) * 8;
        float* outp = bsp + (size_t)u * 2048;
        #pragma unroll
        for (int g2 = 0; g2 < 2; ++g2) {
            const int k = k0 + g2 * 4;
            const int h = (k >> 4) & 1, jt = (k >> 2) & 3;
            float4 o;
            o.x = Ts[h * 16 + quad * 4 + 0][jt * 16 + l15];
            o.y = Ts[h * 16 + quad * 4 + 1][jt * 16 + l15];
            o.z = Ts[h * 16 + quad * 4 + 2][jt * 16 + l15];
            o.w = Ts[h * 16 + quad * 4 + 3][jt * 16 + l15];
            ((float4*)outp)[tid * 2 + g2] = o;
        }
        return;
    }

    const int c = bid & 31;
    const int b = bid >> 5;
    const int m0 = c * 64;
    const float* Kb = K + (size_t)b * Nc * Dc;
    const float* Vb = V + (size_t)b * Nc * Dc;
    const int* imb = imask + b * Nc;

    #pragma unroll
    for (int it = 0; it < 8; ++it) {
        const int idx = it * 256 + tid;
        const int row = idx >> 5;
        const int c4  = idx & 31;
        const int gm  = m0 + row;
        const float msk = imb[gm] ? 1.0f : 0.0f;
        const float4 kf = ((const float4*)(Kb + (size_t)gm * Dc))[c4];
        const float4 vf = ((const float4*)(Vb + (size_t)gm * Dc))[c4];
        bf16x4 kb, vb;
        kb[0] = (__bf16)(kf.x * msk); kb[1] = (__bf16)(kf.y * msk);
        kb[2] = (__bf16)(kf.z * msk); kb[3] = (__bf16)(kf.w * msk);
        vb[0] = (__bf16)(vf.x * msk); vb[1] = (__bf16)(vf.y * msk);
        vb[2] = (__bf16)(vf.z * msk); vb[3] = (__bf16)(vf.w * msk);
        *(bf16x4*)&Ks[row][c4 * 4] = kb;
        *(bf16x4*)&Vs[row][c4 * 4] = vb;
    }
    __syncthreads();

    const size_t chunk_base = (size_t)(b * NCHUNK + c) * CHUNK_ELEMS;
    #pragma unroll
    for (int i = 0; i < 4; ++i) {
        const int s = i * 256 + tid;
        const int f = s >> 6;
        const int l = s & 63;
        const int quad = (l >> 4) & 3;
        const int l15  = l & 15;
        {   // K frag f=jt*4+kd
            const int jt = f >> 2, kd = f & 3;
            const bf16x8 kv = *(const bf16x8*)&Ks[jt * 16 + l15][kd * 32 + quad * 8];
            *(bf16x8*)&Kp[chunk_base + (size_t)f * 512 + l * 8] = kv;
        }
        {   // V frag f=kj*8+dt
            const int kj = f >> 3, dt = f & 7;
            bf16x8 vv;
            #pragma unroll
            for (int j = 0; j < 8; ++j)
                vv[j] = Vs[kj * 32 + quad * 8 + j][dt * 16 + l15];
            *(bf16x8*)&Vp[chunk_base + (size_t)f * 512 + l * 8] = vv;
        }
    }
}

// ---- main: PERSISTENT split-C pipelined flash attention (R4 body) ----
// grid (16, 32) = 512 blocks = exactly 2/CU, resident start-to-finish.
// SPLIT: each slot runs 2-3 units (<=8 chunks each) from SLOT_UNITS, packed
//   LPT to 16-17 chunks/slot (3% imbalance). Removes 768 block launches,
//   dispatch drain, and the residency gaps behind R4's 16.5% occupancy.
// !SPLIT: slot = whole tile, R4's balanced pairing (t, 47-t), direct writes.
// Inner loop is R4's proven pipeline: softmax(c) -> PV(c) -> barrier ->
//   DMA(c+2) -> QK(c+1) with prefetched packed bias as MFMA C-init.
template<bool SPLIT>
__global__ __launch_bounds__(256) void attn_persist(
    const float* __restrict__ Q,
    const __bf16* __restrict__ Kp, const __bf16* __restrict__ Vp,
    const float* __restrict__ biasp, const int* __restrict__ emask,
    float* __restrict__ out, float* __restrict__ part)
{
    __shared__ __align__(16) __bf16 Kl[2][16 * 512];   // 2 x 16KB
    __shared__ __align__(16) __bf16 Vl[2][16 * 512];   // 2 x 16KB
    __shared__ __align__(16) __bf16 Pl[4][16][72];

    const int tid  = threadIdx.x;
    const int w    = tid >> 6;
    const int lane = tid & 63;
    const int quad = lane >> 4;
    const int l15  = lane & 15;
    const int b    = blockIdx.x;
    const int slot = blockIdx.y;

    const float*  Qb  = Q + (size_t)b * Nc * Dc;
    const __bf16* Kpb = Kp + (size_t)b * NCHUNK * CHUNK_ELEMS;
    const __bf16* Vpb = Vp + (size_t)b * NCHUNK * CHUNK_ELEMS;
    const f32x4* bfragbase = (const f32x4*)biasp + (size_t)lane * 8 + (w & 1) * 4;

    for (int j = 0; j < 3; ++j) {
        int t, c0, cend, pidx;
        bool direct;
        if (SPLIT) {
            const int un = SLOT_UNITS[slot][j];
            if (un < 0) break;
            if (un < 8)       { t = un;                  c0 = 0; }
            else if (un < 24) { t = 8  + ((un -  8) >> 1); c0 = ((un -  8) & 1) * 8; }
            else if (un < 48) { t = 16 + (un - 24) / 3;    c0 = ((un - 24) % 3) * 8; }
            else              { t = 24 + ((un - 48) >> 2); c0 = ((un - 48) & 3) * 8; }
            cend = min(t + 1, c0 + 8);
            direct = (un < 8);
            pidx = un - 8;
        } else {
            if (j) break;
            t = (slot < 16) ? slot : (47 - slot);   // pair sums = 33 chunks
            c0 = 0; cend = t + 1; direct = true; pidx = 0;
        }

        const int q0w = t * 64 + w * 16;
        const int t32 = t * 2 + (w >> 1);      // 32-row bias-tile index
        const int fb32 = ftri(t32);
        const f32x4* bfrag = bfragbase;

        // ---- Q fragments (emask + SCALE folded) ----
        bf16x8 qfrag[4];
        {
            const int row = q0w + l15;
            const float qs = emask[b * Nc + row] ? SCALE_F : 0.0f;
            const float4* qr = (const float4*)(Qb + (size_t)row * Dc);
            #pragma unroll
            for (int kd = 0; kd < 4; ++kd) {
                const float4 xx = qr[kd * 8 + quad * 2];
                const float4 yy = qr[kd * 8 + quad * 2 + 1];
                qfrag[kd][0] = (__bf16)(xx.x * qs); qfrag[kd][1] = (__bf16)(xx.y * qs);
                qfrag[kd][2] = (__bf16)(xx.z * qs); qfrag[kd][3] = (__bf16)(xx.w * qs);
                qfrag[kd][4] = (__bf16)(yy.x * qs); qfrag[kd][5] = (__bf16)(yy.y * qs);
                qfrag[kd][6] = (__bf16)(yy.z * qs); qfrag[kd][7] = (__bf16)(yy.w * qs);
            }
        }

        f32x4 oacc[8];
        #pragma unroll
        for (int dt = 0; dt < 8; ++dt) { oacc[dt][0]=0.f; oacc[dt][1]=0.f; oacc[dt][2]=0.f; oacc[dt][3]=0.f; }
        float mrun[4] = {-INFINITY, -INFINITY, -INFINITY, -INFINITY};
        float lrun[4] = {0.f, 0.f, 0.f, 0.f};

        const int nch = cend - c0;

        // ---- prologue: DMA chunk c0 -> buf0; bias(c0) ----
        #pragma unroll
        for (int i = 0; i < 4; ++i) {
            const int seg = w * 4 + i;
            gload_lds16(Kpb + (size_t)c0 * CHUNK_ELEMS + seg * 512 + lane * 8, &Kl[0][seg * 512]);
            gload_lds16(Vpb + (size_t)c0 * CHUNK_ELEMS + seg * 512 + lane * 8, &Vl[0][seg * 512]);
        }
        f32x4 binit[4];
        #pragma unroll
        for (int jt = 0; jt < 4; ++jt)
            binit[jt] = bfrag[(size_t)(fb32 + c0) * 512 + jt];
        __syncthreads();   // drain: chunk-c0 DMA landed

        // ---- QK(c0) with bias as C-init ----
        f32x4 sc[4];
        #pragma unroll
        for (int jt = 0; jt < 4; ++jt) sc[jt] = binit[jt];
        #pragma unroll
        for (int jt = 0; jt < 4; ++jt)
            #pragma unroll
            for (int kd = 0; kd < 4; ++kd) {
                const bf16x8 bfr = *(const bf16x8*)&Kl[0][(jt * 4 + kd) * 512 + lane * 8];
                sc[jt] = __builtin_amdgcn_mfma_f32_16x16x32_bf16(qfrag[kd], bfr, sc[jt], 0, 0, 0);
            }
        if (nch > 1) {
            #pragma unroll
            for (int i = 0; i < 4; ++i) {
                const int seg = w * 4 + i;
                gload_lds16(Kpb + (size_t)(c0 + 1) * CHUNK_ELEMS + seg * 512 + lane * 8, &Kl[1][seg * 512]);
                gload_lds16(Vpb + (size_t)(c0 + 1) * CHUNK_ELEMS + seg * 512 + lane * 8, &Vl[1][seg * 512]);
            }
            #pragma unroll
            for (int jt = 0; jt < 4; ++jt)
                binit[jt] = bfrag[(size_t)(fb32 + c0 + 1) * 512 + jt];
        }

        for (int c = c0; c < cend; ++c) {
            const int cb = (c - c0) & 1;

            // ---- causal mask on the diagonal chunk (bias already in sc) ----
            if (c == t) {
                const int m0 = c * 64;
                #pragma unroll
                for (int jt = 0; jt < 4; ++jt)
                    #pragma unroll
                    for (int reg = 0; reg < 4; ++reg) {
                        const int gr = q0w + quad * 4 + reg;
                        const int gc = m0 + jt * 16 + l15;
                        if (gc > gr) sc[jt][reg] = -INFINITY;
                    }
            }

            // ---- online softmax; exact rescale-skip when no row max grows ----
            float mx[4];
            int grow = 0;
            #pragma unroll
            for (int reg = 0; reg < 4; ++reg) {
                float m = fmaxf(fmaxf(sc[0][reg], sc[1][reg]), fmaxf(sc[2][reg], sc[3][reg]));
                m = rmax16(m);
                mx[reg] = m;
                grow |= (m > mrun[reg]);
            }
            if (__any(grow)) {   // wave-uniform; skip path is numerically exact
                #pragma unroll
                for (int reg = 0; reg < 4; ++reg) {
                    const float mn = fmaxf(mrun[reg], mx[reg]);
                    const float alpha = __expf(mrun[reg] - mn);  // first chunk: exp(-inf)=0
                    mrun[reg] = mn;
                    lrun[reg] *= alpha;
                    #pragma unroll
                    for (int dt = 0; dt < 8; ++dt) oacc[dt][reg] *= alpha;
                }
            }
            #pragma unroll
            for (int reg = 0; reg < 4; ++reg) {
                float ls = 0.f;
                #pragma unroll
                for (int jt = 0; jt < 4; ++jt) {
                    const float pv = __expf(sc[jt][reg] - mrun[reg]);  // masked: exp(-inf)=0
                    sc[jt][reg] = pv;
                    ls += pv;
                }
                lrun[reg] += rsum16(ls);
            }

            // ---- P: C-layout -> LDS -> A-layout ----
            #pragma unroll
            for (int jt = 0; jt < 4; ++jt)
                #pragma unroll
                for (int reg = 0; reg < 4; ++reg)
                    Pl[w][quad * 4 + reg][jt * 16 + l15] = (__bf16)sc[jt][reg];
            // same-wave write->read; compiler inserts lgkmcnt wait

            // ---- O += P V ----
            #pragma unroll
            for (int kj = 0; kj < 2; ++kj) {
                const bf16x8 pa = *(const bf16x8*)&Pl[w][l15][kj * 32 + quad * 8];
                #pragma unroll
                for (int dt = 0; dt < 8; ++dt) {
                    const bf16x8 vb = *(const bf16x8*)&Vl[cb][(kj * 8 + dt) * 512 + lane * 8];
                    oacc[dt] = __builtin_amdgcn_mfma_f32_16x16x32_bf16(pa, vb, oacc[dt], 0, 0, 0);
                }
            }

            // single barrier: all waves done reading Kl[cb]/Vl[cb]; vmcnt drain
            // covers DMA(c+1) (issued a full iteration ago -> near-free).
            __syncthreads();

            const bool n1 = (c + 1) < cend;
            const bool n2 = (c + 2) < cend;

            // ---- DMA chunk c+2 into buf[cb] (K(c)/V(c) both retired) ----
            if (n2) {
                const size_t off = (size_t)(c + 2) * CHUNK_ELEMS;
                #pragma unroll
                for (int i = 0; i < 4; ++i) {
                    const int seg = w * 4 + i;
                    gload_lds16(Kpb + off + seg * 512 + lane * 8, &Kl[cb][seg * 512]);
                    gload_lds16(Vpb + off + seg * 512 + lane * 8, &Vl[cb][seg * 512]);
                }
            }

            // ---- QK(c+1) from Kl[cb^1]; prefetched bias as C-init ----
            if (n1) {
                #pragma unroll
                for (int jt = 0; jt < 4; ++jt) sc[jt] = binit[jt];
                #pragma unroll
                for (int jt = 0; jt < 4; ++jt)
                    #pragma unroll
                    for (int kd = 0; kd < 4; ++kd) {
                        const bf16x8 bfr = *(const bf16x8*)&Kl[cb ^ 1][(jt * 4 + kd) * 512 + lane * 8];
                        sc[jt] = __builtin_amdgcn_mfma_f32_16x16x32_bf16(qfrag[kd], bfr, sc[jt], 0, 0, 0);
                    }
            }
            if (n2) {
                #pragma unroll
                for (int jt = 0; jt < 4; ++jt)
                    binit[jt] = bfrag[(size_t)(fb32 + c + 2) * 512 + jt];
            }
        }

        // ---- epilogue ----
        if (direct) {
            #pragma unroll
            for (int reg = 0; reg < 4; ++reg) {
                const float inv = 1.0f / lrun[reg];
                const int gr = q0w + quad * 4 + reg;
                float* orow = out + ((size_t)b * Nc + gr) * Dc;
                #pragma unroll
                for (int dt = 0; dt < 8; ++dt)
                    orow[dt * 16 + l15] = oacc[dt][reg] * inv;
            }
        } else {
            float* pb = part + (size_t)(b * 72 + pidx) * PART_FLOATS;
            #pragma unroll
            for (int reg = 0; reg < 4; ++reg) {
                const int lr = w * 16 + quad * 4 + reg;
                #pragma unroll
                for (int dt = 0; dt < 8; ++dt)
                    pb[lr * 128 + dt * 16 + l15] = oacc[dt][reg];
                if (l15 == 0) {
                    pb[8192 + lr] = mrun[reg];
                    pb[8256 + lr] = lrun[reg];
                }
            }
        }
        // next unit's prologue DMA is safe: all Kl/Vl reads completed before
        // the final barrier of this unit's loop.
    }
}

// ---- merge <=4 split-C partials per (b, tile t=8..31) ----
__global__ __launch_bounds__(256) void merge_parts(
    const float* __restrict__ part, float* __restrict__ out)
{
    const int b = blockIdx.x;
    const int t = 8 + blockIdx.y;
    const int S = (t < 16) ? 2 : ((t < 24) ? 3 : 4);
    const int pbase = (t < 16) ? 2 * (t - 8)
                    : (t < 24) ? 16 + 3 * (t - 16)
                               : 40 + 4 * (t - 24);
    const int r  = threadIdx.x >> 2;       // row 0..63
    const int cq = threadIdx.x & 3;        // col quarter (32 cols)
    const float* p0 = part + (size_t)(b * 72 + pbase) * PART_FLOATS;

    float m[4], a[4];
    float mstar = -INFINITY;
    #pragma unroll
    for (int s = 0; s < 4; ++s)
        if (s < S) { m[s] = p0[(size_t)s * PART_FLOATS + 8192 + r]; mstar = fmaxf(mstar, m[s]); }
    float lsum = 0.f;
    #pragma unroll
    for (int s = 0; s < 4; ++s)
        if (s < S) {
            a[s] = __expf(m[s] - mstar);
            lsum += p0[(size_t)s * PART_FLOATS + 8256 + r] * a[s];
        }
    const float inv = 1.0f / lsum;

    float* orow = out + ((size_t)b * Nc + t * 64 + r) * Dc + cq * 32;
    #pragma unroll
    for (int i = 0; i < 8; ++i) {
        float x = 0.f, y = 0.f, z = 0.f, ww = 0.f;
        #pragma unroll
        for (int s = 0; s < 4; ++s)
            if (s < S) {
                const f32x4 v = *(const f32x4*)&p0[(size_t)s * PART_FLOATS + r * 128 + cq * 32 + i * 4];
                x += v[0] * a[s]; y += v[1] * a[s]; z += v[2] * a[s]; ww += v[3] * a[s];
            }
        f32x4 o; o[0] = x * inv; o[1] = y * inv; o[2] = z * inv; o[3] = ww * inv;
        *(f32x4*)&orow[i * 4] = o;
    }
}

// ---- legacy fallback (in-kernel staging, 4 bias reads) for tiny ws ----
__global__ __launch_bounds__(256) void attn_mfma_legacy(
    const float* __restrict__ Q, const float* __restrict__ K, const float* __restrict__ V,
    const float* __restrict__ p0, const float* __restrict__ p1,
    const float* __restrict__ p2, const float* __restrict__ p3,
    const int* __restrict__ imask, const int* __restrict__ emask,
    float* __restrict__ out)
{
    __shared__ __align__(16) __bf16 Klds[64][136];
    __shared__ __align__(16) __bf16 Vt[128][72];
    __shared__ __align__(16) __bf16 Plds[4][16][72];
    const int tid  = threadIdx.x;
    const int w    = tid >> 6;
    const int lane = tid & 63;
    const int quad = lane >> 4;
    const int l15  = lane & 15;
    const int b = blockIdx.y;
    const int x = blockIdx.x, yy = blockIdx.y;
    const int ti = (yy < 8) ? x : (31 - x);
    const int q0 = ti * 64, q0w = q0 + w * 16;
    const float* Qb = Q + (size_t)b * Nc * Dc;
    const float* Kb = K + (size_t)b * Nc * Dc;
    const float* Vb = V + (size_t)b * Nc * Dc;
    const int* imb = imask + b * Nc;

    bf16x8 qfrag[4];
    {
        const int row = q0w + l15;
        const float qs = emask[b * Nc + row] ? SCALE_F : 0.0f;
        const float4* qr = (const float4*)(Qb + (size_t)row * Dc);
        #pragma unroll
        for (int kd = 0; kd < 4; ++kd) {
            const float4 xv = qr[kd * 8 + quad * 2];
            const float4 yv = qr[kd * 8 + quad * 2 + 1];
            qfrag[kd][0]=(__bf16)(xv.x*qs); qfrag[kd][1]=(__bf16)(xv.y*qs);
            qfrag[kd][2]=(__bf16)(xv.z*qs); qfrag[kd][3]=(__bf16)(xv.w*qs);
            qfrag[kd][4]=(__bf16)(yv.x*qs); qfrag[kd][5]=(__bf16)(yv.y*qs);
            qfrag[kd][6]=(__bf16)(yv.z*qs); qfrag[kd][7]=(__bf16)(yv.w*qs);
        }
    }
    f32x4 oacc[8];
    #pragma unroll
    for (int dt = 0; dt < 8; ++dt){oacc[dt][0]=0.f;oacc[dt][1]=0.f;oacc[dt][2]=0.f;oacc[dt][3]=0.f;}
    float mrun[4]={-INFINITY,-INFINITY,-INFINITY,-INFINITY}, lrun[4]={0.f,0.f,0.f,0.f};

    for (int m0 = 0; m0 <= q0; m0 += 64) {
        __syncthreads();
        #pragma unroll
        for (int it = 0; it < 8; ++it) {
            const int idx = it * 256 + tid;
            const int row = idx >> 5, c4 = idx & 31;
            const int gm = m0 + row;
            const float msk = imb[gm] ? 1.0f : 0.0f;
            const float4 kf = ((const float4*)(Kb + (size_t)gm * Dc))[c4];
            const float4 vf = ((const float4*)(Vb + (size_t)gm * Dc))[c4];
            bf16x4 kb;
            kb[0]=(__bf16)(kf.x*msk); kb[1]=(__bf16)(kf.y*msk);
            kb[2]=(__bf16)(kf.z*msk); kb[3]=(__bf16)(kf.w*msk);
            *(bf16x4*)&Klds[row][c4*4] = kb;
            Vt[c4*4+0][row]=(__bf16)(vf.x*msk); Vt[c4*4+1][row]=(__bf16)(vf.y*msk);
            Vt[c4*4+2][row]=(__bf16)(vf.z*msk); Vt[c4*4+3][row]=(__bf16)(vf.w*msk);
        }
        __syncthreads();
        f32x4 sc[4];
        #pragma unroll
        for (int jt = 0; jt < 4; ++jt){sc[jt][0]=0.f;sc[jt][1]=0.f;sc[jt][2]=0.f;sc[jt][3]=0.f;}
        #pragma unroll
        for (int jt = 0; jt < 4; ++jt)
            #pragma unroll
            for (int kd = 0; kd < 4; ++kd) {
                const bf16x8 bfr = *(const bf16x8*)&Klds[jt*16+l15][kd*32+quad*8];
                sc[jt] = __builtin_amdgcn_mfma_f32_16x16x32_bf16(qfrag[kd], bfr, sc[jt], 0, 0, 0);
            }
        #pragma unroll
        for (int jt = 0; jt < 4; ++jt)
            #pragma unroll
            for (int reg = 0; reg < 4; ++reg) {
                const int gr = q0w + quad*4 + reg;
                const int gc = m0 + jt*16 + l15;
                const size_t boff = (size_t)gr * Nc + gc;
                const float bsx = p0[boff] + p1[boff] + p2[boff] + p3[boff];
                const float v = sc[jt][reg] + bsx;
                sc[jt][reg] = (gc > gr) ? -INFINITY : v;
            }
        #pragma unroll
        for (int reg = 0; reg < 4; ++reg) {
            float mx = fmaxf(fmaxf(sc[0][reg], sc[1][reg]), fmaxf(sc[2][reg], sc[3][reg]));
            mx = rmax16(mx);
            const float mn = fmaxf(mrun[reg], mx);
            const float alpha = __expf(mrun[reg] - mn);
            mrun[reg] = mn; lrun[reg] *= alpha;
            #pragma unroll
            for (int dt = 0; dt < 8; ++dt) oacc[dt][reg] *= alpha;
            float ls = 0.f;
            #pragma unroll
            for (int jt = 0; jt < 4; ++jt) {
                const float pv = __expf(sc[jt][reg] - mn);
                sc[jt][reg] = pv; ls += pv;
            }
            lrun[reg] += rsum16(ls);
        }
        #pragma unroll
        for (int jt = 0; jt < 4; ++jt)
            #pragma unroll
            for (int reg = 0; reg < 4; ++reg)
                Plds[w][quad*4+reg][jt*16+l15] = (__bf16)sc[jt][reg];
        #pragma unroll
        for (int kj = 0; kj < 2; ++kj) {
            const bf16x8 pa = *(const bf16x8*)&Plds[w][l15][kj*32+quad*8];
            #pragma unroll
            for (int dt = 0; dt < 8; ++dt) {
                const bf16x8 vb = *(const bf16x8*)&Vt[dt*16+l15][kj*32+quad*8];
                oacc[dt] = __builtin_amdgcn_mfma_f32_16x16x32_bf16(pa, vb, oacc[dt], 0, 0, 0);
            }
        }
    }
    #pragma unroll
    for (int reg = 0; reg < 4; ++reg) {
        const float inv = 1.0f / lrun[reg];
        const int gr = q0w + quad*4 + reg;
        float* orow = out + ((size_t)b * Nc + gr) * Dc;
        #pragma unroll
        for (int dt = 0; dt < 8; ++dt)
            orow[dt*16+l15] = oacc[dt][reg] * inv;
    }
}

extern "C" void kernel_launch(void* const* d_in, const int* in_sizes, int n_in,
                              void* d_out, int out_size, void* d_ws, size_t ws_size,
                              hipStream_t stream) {
    const float* Q  = (const float*)d_in[0];
    const float* K  = (const float*)d_in[1];
    const float* V  = (const float*)d_in[2];
    const float* b0 = (const float*)d_in[3];
    const float* b1 = (const float*)d_in[4];
    const float* b2 = (const float*)d_in[5];
    const float* b3 = (const float*)d_in[6];
    const int* im   = (const int*)d_in[7];
    const int* em   = (const int*)d_in[8];
    float* out      = (float*)d_out;

    const size_t need_full  = KPACK_BYTES + VPACK_BYTES + BIASP_BYTES;
    const size_t need_split = need_full + PART_BYTES;

    if (ws_size >= need_full) {
        __bf16* Kp  = (__bf16*)d_ws;
        __bf16* Vp  = (__bf16*)((char*)d_ws + KPACK_BYTES);
        float*  bsp = (float*)((char*)d_ws + KPACK_BYTES + VPACK_BYTES);
        float*  prt = (float*)((char*)d_ws + need_full);
        prep_fused<<<512 + NUNITS, 256, 0, stream>>>(
            K, V, im, b0, b1, b2, b3, Kp, Vp, bsp);
        if (ws_size >= need_split) {
            attn_persist<true><<<dim3(Bc, 32), 256, 0, stream>>>(
                Q, Kp, Vp, bsp, em, out, prt);
            merge_parts<<<dim3(Bc, 24), 256, 0, stream>>>(prt, out);
        } else {
            attn_persist<false><<<dim3(Bc, 32), 256, 0, stream>>>(
                Q, Kp, Vp, bsp, em, out, nullptr);
        }
    } else {
        attn_mfma_legacy<<<dim3(NCHUNK, Bc), 256, 0, stream>>>(
            Q, K, V, b0, b1, b2, b3, im, em, out);
    }
}